// Round 14
// baseline (3465.786 us; speedup 1.0000x reference)
//
#include <hip/hip_runtime.h>
#include <stdint.h>
#include <math.h>

typedef unsigned short ushort_t;
typedef __attribute__((ext_vector_type(8))) short bf16x8;
typedef __attribute__((ext_vector_type(4))) float f32x4;

#define T1_ 32

__device__ __forceinline__ float bf2f(ushort_t u) {
  union { unsigned int i; float f; } v; v.i = ((unsigned int)u) << 16; return v.f;
}
__device__ __forceinline__ ushort_t f2bf(float f) {
  union { float f; unsigned int i; } v; v.f = f;
  unsigned int x = v.i;
  return (ushort_t)((x + 0x7FFFu + ((x >> 16) & 1u)) >> 16); // RNE
}
__device__ __forceinline__ float sigm(float x) { return 1.f / (1.f + expf(-x)); }

__device__ __forceinline__ void gld16(const ushort_t* g, ushort_t* l) {
  __builtin_amdgcn_global_load_lds(
      (const __attribute__((address_space(1))) unsigned int*)g,
      (__attribute__((address_space(3))) unsigned int*)l, 16, 0, 0);
}

// XOR-chunk swizzle (R11, verified): staging lane l -> (row=l>>2, chunk=(l^(l>>2)^(l>>4))&3);
// reader lane l wants (row r=l&15, chunk q=l>>4) -> slot (r<<2)|((q^r^(r>>2))&3).
// Coalesced 64B/row staging + conflict-free (2-way) ds_read_b128.

__global__ __launch_bounds__(256) void cvt_k(const float* src, ushort_t* dst,
                                             long long n, int cols, int src_ld, int src_off) {
  const long long idx = (long long)blockIdx.x * 256 + threadIdx.x;
  if (idx >= n) return;
  const long long row = idx / cols;
  const int col = (int)(idx - row * cols);
  dst[idx] = f2bf(src[row * src_ld + src_off + col]);
}

__global__ __launch_bounds__(256) void wpe_k(const float* Wesp, float* wpe) {
  const int i = blockIdx.x * 256 + threadIdx.x;
  if (i >= 1024 * 6) return;
  const int n = i / 6, j = i % 6;
  float s = 0.f;
#pragma unroll
  for (int r = 0; r < 4; ++r) s += Wesp[(long long)n * 536 + j + 6 * r];
  wpe[i] = s;
}

__global__ void marker_k(float* out, float K) {
  if (threadIdx.x == 0 && blockIdx.x == 0) out[0] = K;
}

// ---- one-time batched obs GEMM: OBSQ[32768 x 1024] = obsb @ Wesq[:, :1024]^T (bf16 out) ----
// BM=64, BN=128, BK=32; 256 thr (4 waves 2x2); swizzled, dbuf. grid (8, 512).
struct ObsqArgs { const ushort_t* A; const ushort_t* W; ushort_t* out; };
__global__ __launch_bounds__(256) void obsq_k(ObsqArgs g) {
  __shared__ __align__(16) ushort_t As[2][2048];
  __shared__ __align__(16) ushort_t Ws[2][4096];
  const int tid = threadIdx.x;
  const int lane = tid & 63, wv = tid >> 6;
  const int wm = wv >> 1, wn = wv & 1;
  const int bn0 = blockIdx.x * 128, bm0 = blockIdx.y * 64;
  const int srow = lane >> 2;
  const int sch8 = ((lane ^ (lane >> 2) ^ (lane >> 4)) & 3) * 8;
  const int rr = lane & 15, qq = lane >> 4;
  const int rslot8 = (((rr << 2) | ((qq ^ rr ^ (rr >> 2)) & 3)) * 8);

  f32x4 acc[2][4];
#pragma unroll
  for (int i = 0; i < 2; ++i)
#pragma unroll
    for (int j = 0; j < 4; ++j) acc[i][j] = (f32x4){0.f, 0.f, 0.f, 0.f};

  auto stage = [&](int buf, int kt) {
    const int k0 = kt * 32;
    gld16(g.A + (size_t)(bm0 + wv * 16 + srow) * 1024 + k0 + sch8, &As[buf][wv * 512]);
    gld16(g.W + (size_t)(bn0 + wv * 16 + srow) * 1536 + k0 + sch8, &Ws[buf][wv * 512]);
    gld16(g.W + (size_t)(bn0 + 64 + wv * 16 + srow) * 1536 + k0 + sch8,
          &Ws[buf][2048 + wv * 512]);
  };

  stage(0, 0);
  __syncthreads();
  int cur = 0;
#pragma unroll 1
  for (int kt = 0; kt < 32; ++kt) {
    if (kt + 1 < 32) stage(cur ^ 1, kt + 1);
    bf16x8 a[2], b[4];
#pragma unroll
    for (int i = 0; i < 2; ++i)
      a[i] = *(const bf16x8*)&As[cur][(wm * 2 + i) * 512 + rslot8];
#pragma unroll
    for (int j = 0; j < 4; ++j)
      b[j] = *(const bf16x8*)&Ws[cur][(wn * 4 + j) * 512 + rslot8];
#pragma unroll
    for (int i = 0; i < 2; ++i)
#pragma unroll
      for (int j = 0; j < 4; ++j)
        acc[i][j] = __builtin_amdgcn_mfma_f32_16x16x32_bf16(a[i], b[j], acc[i][j], 0, 0, 0);
    __syncthreads();
    cur ^= 1;
  }

  const int r15 = lane & 15, rq = (lane >> 4) * 4;
#pragma unroll
  for (int i = 0; i < 2; ++i)
#pragma unroll
    for (int j = 0; j < 4; ++j) {
      const int col = bn0 + wn * 64 + j * 16 + r15;
#pragma unroll
      for (int q = 0; q < 4; ++q) {
        const int row = bm0 + wm * 32 + i * 16 + rq + q;
        g.out[(size_t)row * 1024 + col] = f2bf(acc[i][j][q]);
      }
    }
}

// ---- fused 2-sided GEMM: BM=32, BN=128, BK=32; 256 thr (4 waves, wn=wv); dbuf ----
struct MMSide {
  const ushort_t* a0; const ushort_t* a1; const ushort_t* a2;
  int kd0, kd1, kd2;
  int coff0, coff1, coff2;
  const ushort_t* W; int ldw;
  const float* bias;
  ushort_t* outb;
  int dopose;
  const ushort_t* extrab;   // optional full-width bf16 pre-activation add [1024x1024]
};
struct MM2Args { MMSide s[2]; const float* poses_t; const float* wpe; };

__global__ __launch_bounds__(256) void mm2_k(MM2Args g) {
  const MMSide S = g.s[blockIdx.z];
  __shared__ __align__(16) ushort_t As[2][1024];
  __shared__ __align__(16) ushort_t Ws[2][4096];
  const int tid = threadIdx.x;
  const int lane = tid & 63, wv = tid >> 6;
  const int wn = wv;
  const int bn0 = blockIdx.x * 128, bm0 = blockIdx.y * 32;
  const int srow = lane >> 2;
  const int sch8 = ((lane ^ (lane >> 2) ^ (lane >> 4)) & 3) * 8;
  const int rr = lane & 15, qq = lane >> 4;
  const int rslot8 = (((rr << 2) | ((qq ^ rr ^ (rr >> 2)) & 3)) * 8);

  f32x4 acc[2][2];
#pragma unroll
  for (int i = 0; i < 2; ++i)
#pragma unroll
    for (int j = 0; j < 2; ++j) acc[i][j] = (f32x4){0.f, 0.f, 0.f, 0.f};

  const int nk0 = S.kd0 >> 5, nk1 = S.kd1 >> 5, nk2 = S.kd2 >> 5;
  const int c1 = nk0, c2 = nk0 + nk1, nkt = c2 + nk2;

  auto stage = [&](int buf, int ktg) {
    const ushort_t* ab; int ktl, kdim, cf;
    if (ktg < c1)      { ab = S.a0; ktl = ktg;      kdim = S.kd0; cf = S.coff0; }
    else if (ktg < c2) { ab = S.a1; ktl = ktg - c1; kdim = S.kd1; cf = S.coff1; }
    else               { ab = S.a2; ktl = ktg - c2; kdim = S.kd2; cf = S.coff2; }
    const int k0 = ktl * 32;
    gld16(S.W + cf + (size_t)(bn0 + wv * 16 + srow) * S.ldw + k0 + sch8, &Ws[buf][wv * 512]);
    gld16(S.W + cf + (size_t)(bn0 + 64 + wv * 16 + srow) * S.ldw + k0 + sch8,
          &Ws[buf][(wv + 4) * 512]);
    if (wv < 2)
      gld16(ab + (size_t)(bm0 + wv * 16 + srow) * kdim + k0 + sch8, &As[buf][wv * 512]);
  };

  stage(0, 0);
  __syncthreads();
  int cur = 0;
#pragma unroll 1
  for (int ktg = 0; ktg < nkt; ++ktg) {
    if (ktg + 1 < nkt) stage(cur ^ 1, ktg + 1);
    bf16x8 a[2], b[2];
#pragma unroll
    for (int i = 0; i < 2; ++i)
      a[i] = *(const bf16x8*)&As[cur][i * 512 + rslot8];
#pragma unroll
    for (int j = 0; j < 2; ++j)
      b[j] = *(const bf16x8*)&Ws[cur][(wn * 2 + j) * 512 + rslot8];
#pragma unroll
    for (int i = 0; i < 2; ++i)
#pragma unroll
      for (int j = 0; j < 2; ++j)
        acc[i][j] = __builtin_amdgcn_mfma_f32_16x16x32_bf16(a[i], b[j], acc[i][j], 0, 0, 0);
    __syncthreads();
    cur ^= 1;
  }

  const int r15 = lane & 15, rq = (lane >> 4) * 4;
#pragma unroll
  for (int i = 0; i < 2; ++i) {
#pragma unroll
    for (int j = 0; j < 2; ++j) {
      const int col = bn0 + wn * 32 + j * 16 + r15;
      const float bs = S.bias[col];
#pragma unroll
      for (int q = 0; q < 4; ++q) {
        const int row = bm0 + i * 16 + rq + q;
        float v = acc[i][j][q] + bs;
        if (S.extrab) v += bf2f(S.extrab[(size_t)row * 1024 + col]);
        if (S.dopose) {
          float s = 0.f;
#pragma unroll
          for (int jj = 0; jj < 6; ++jj)
            s += g.poses_t[(long long)row * 6 + jj] * g.wpe[col * 6 + jj];
          v += s;
        }
        v = fmaxf(v, 0.f);
        S.outb[(size_t)row * 1024 + col] = f2bf(v);
      }
    }
  }
}

// ---- fused 2-sided GRU: BM=64, BN=64, 256 thr (4 waves 2x2), dbuf ----
struct GruSide {
  const ushort_t* x;
  const ushort_t* hb;
  const float* hf;
  const ushort_t* wih; const ushort_t* whh;
  const float* bih; const float* bhh;
  float* dst; ushort_t* dstb;    // ping-pong: dstb != hb
};
struct Gru2Args { GruSide s[2]; };

__global__ __launch_bounds__(256) void gru2_k(Gru2Args g) {
  const GruSide S = g.s[blockIdx.z];
  __shared__ __align__(16) ushort_t lds[2][16384];  // 64 KB
  const int tid = threadIdx.x;
  const int lane = tid & 63, wv = tid >> 6;
  const int wm = wv >> 1, wn = wv & 1;
  const int bn0 = blockIdx.x * 64, bm0 = blockIdx.y * 64;
  const int srow = lane >> 2;
  const int sch8 = ((lane ^ (lane >> 2) ^ (lane >> 4)) & 3) * 8;
  const int rr = lane & 15, qq = lane >> 4;
  const int rslot8 = (((rr << 2) | ((qq ^ rr ^ (rr >> 2)) & 3)) * 8);

  f32x4 aR[2][2], aZ[2][2], aNI[2][2], aNH[2][2];
#pragma unroll
  for (int i = 0; i < 2; ++i)
#pragma unroll
    for (int j = 0; j < 2; ++j) {
      aR[i][j] = (f32x4){0.f,0.f,0.f,0.f}; aZ[i][j] = (f32x4){0.f,0.f,0.f,0.f};
      aNI[i][j] = (f32x4){0.f,0.f,0.f,0.f}; aNH[i][j] = (f32x4){0.f,0.f,0.f,0.f};
    }

  auto stage = [&](int buf, int kt) {
    const int k0 = kt * 32;
#pragma unroll
    for (int u = 0; u < 8; ++u) {
      const int G = wv * 8 + u;
      if (G < 4)
        gld16(S.x + (size_t)(bm0 + G * 16 + srow) * 1024 + k0 + sch8, &lds[buf][G * 512]);
      else if (G < 8)
        gld16(S.hb + (size_t)(bm0 + (G - 4) * 16 + srow) * 1024 + k0 + sch8, &lds[buf][G * 512]);
      else {
        const int wch = G - 8, gg = wch >> 2, rc = wch & 3;
        const ushort_t* base = (gg < 3) ? S.wih : S.whh;
        const int gr = (gg < 3 ? gg : gg - 3) * 1024 + bn0 + rc * 16 + srow;
        gld16(base + (size_t)gr * 1024 + k0 + sch8, &lds[buf][G * 512]);
      }
    }
  };

  stage(0, 0);
  __syncthreads();
  int cur = 0;
#pragma unroll 1
  for (int kt = 0; kt < 32; ++kt) {
    if (kt + 1 < 32) stage(cur ^ 1, kt + 1);
    bf16x8 ax[2], ah[2], w[6][2];
#pragma unroll
    for (int i = 0; i < 2; ++i) {
      ax[i] = *(const bf16x8*)&lds[cur][(wm * 2 + i) * 512 + rslot8];
      ah[i] = *(const bf16x8*)&lds[cur][(4 + wm * 2 + i) * 512 + rslot8];
    }
#pragma unroll
    for (int gg = 0; gg < 6; ++gg)
#pragma unroll
      for (int j = 0; j < 2; ++j)
        w[gg][j] = *(const bf16x8*)&lds[cur][(8 + gg * 4 + wn * 2 + j) * 512 + rslot8];
#pragma unroll
    for (int i = 0; i < 2; ++i)
#pragma unroll
      for (int j = 0; j < 2; ++j) {
        aR[i][j]  = __builtin_amdgcn_mfma_f32_16x16x32_bf16(ax[i], w[0][j], aR[i][j], 0, 0, 0);
        aR[i][j]  = __builtin_amdgcn_mfma_f32_16x16x32_bf16(ah[i], w[3][j], aR[i][j], 0, 0, 0);
        aZ[i][j]  = __builtin_amdgcn_mfma_f32_16x16x32_bf16(ax[i], w[1][j], aZ[i][j], 0, 0, 0);
        aZ[i][j]  = __builtin_amdgcn_mfma_f32_16x16x32_bf16(ah[i], w[4][j], aZ[i][j], 0, 0, 0);
        aNI[i][j] = __builtin_amdgcn_mfma_f32_16x16x32_bf16(ax[i], w[2][j], aNI[i][j], 0, 0, 0);
        aNH[i][j] = __builtin_amdgcn_mfma_f32_16x16x32_bf16(ah[i], w[5][j], aNH[i][j], 0, 0, 0);
      }
    __syncthreads();
    cur ^= 1;
  }

  const int r15 = lane & 15, rq = (lane >> 4) * 4;
#pragma unroll
  for (int j = 0; j < 2; ++j) {
    const int col = bn0 + wn * 32 + j * 16 + r15;
    const float brz = S.bih[col] + S.bhh[col];
    const float bzz = S.bih[col + 1024] + S.bhh[col + 1024];
    const float bni = S.bih[col + 2048], bnh = S.bhh[col + 2048];
#pragma unroll
    for (int i = 0; i < 2; ++i) {
#pragma unroll
      for (int q = 0; q < 4; ++q) {
        const int row = bm0 + wm * 32 + i * 16 + rq + q;
        const float r = sigm(aR[i][j][q] + brz);
        const float z = sigm(aZ[i][j][q] + bzz);
        const float ng = tanhf(aNI[i][j][q] + bni + r * (aNH[i][j][q] + bnh));
        const size_t o = (size_t)row * 1024 + col;
        const float bnew = (1.f - z) * ng + z * S.hf[o];
        S.dst[o] = bnew;
        S.dstb[o] = f2bf(bnew);
      }
    }
  }
}

// ---- fused 2-sided head: BM=32, BN=32, 256 thr (4 waves 2x2), dbuf ----
struct HeadSide {
  const ushort_t* hh;
  const ushort_t* Ws;    // [512x1024]: rows [0,256)=mean, [256,512)=raw
  const float* bs;
  const float* noise;
  float* omean; float* ostd; float* ostate;
  ushort_t* stateb;
};
struct Head2Args { HeadSide s[2]; };

__global__ __launch_bounds__(256) void head2_k(Head2Args g) {
  const HeadSide S = g.s[blockIdx.z];
  __shared__ __align__(16) ushort_t lds[2][3072];
  const int tid = threadIdx.x;
  const int lane = tid & 63, wv = tid >> 6;
  const int wm = wv >> 1, wn = wv & 1;
  const int bn0 = blockIdx.x * 32, bm0 = blockIdx.y * 32;
  const int srow = lane >> 2;
  const int sch8 = ((lane ^ (lane >> 2) ^ (lane >> 4)) & 3) * 8;
  const int rr = lane & 15, qq = lane >> 4;
  const int rslot8 = (((rr << 2) | ((qq ^ rr ^ (rr >> 2)) & 3)) * 8);

  f32x4 acc[2];
#pragma unroll
  for (int gg = 0; gg < 2; ++gg) acc[gg] = (f32x4){0.f, 0.f, 0.f, 0.f};

  auto stage = [&](int buf, int kt) {
    const int k0 = kt * 32;
    if (wv < 2) {
      gld16(S.hh + (size_t)(bm0 + wv * 16 + srow) * 1024 + k0 + sch8, &lds[buf][wv * 512]);
      gld16(S.Ws + (size_t)(bn0 + wv * 16 + srow) * 1024 + k0 + sch8, &lds[buf][(2 + wv) * 512]);
    } else {
      gld16(S.Ws + (size_t)(256 + bn0 + (wv - 2) * 16 + srow) * 1024 + k0 + sch8,
            &lds[buf][(2 + wv) * 512]);
    }
  };

  stage(0, 0);
  __syncthreads();
  int cur = 0;
#pragma unroll 1
  for (int kt = 0; kt < 32; ++kt) {
    if (kt + 1 < 32) stage(cur ^ 1, kt + 1);
    const bf16x8 a = *(const bf16x8*)&lds[cur][wm * 512 + rslot8];
    const bf16x8 w0 = *(const bf16x8*)&lds[cur][(2 + wn) * 512 + rslot8];
    const bf16x8 w1 = *(const bf16x8*)&lds[cur][(4 + wn) * 512 + rslot8];
    acc[0] = __builtin_amdgcn_mfma_f32_16x16x32_bf16(a, w0, acc[0], 0, 0, 0);
    acc[1] = __builtin_amdgcn_mfma_f32_16x16x32_bf16(a, w1, acc[1], 0, 0, 0);
    __syncthreads();
    cur ^= 1;
  }

  const int r15 = lane & 15, rq = (lane >> 4) * 4;
  const int col = bn0 + wn * 16 + r15;
  const float bm_ = S.bs[col];
  const float bsd = S.bs[col + 256];
#pragma unroll
  for (int q = 0; q < 4; ++q) {
    const int row = bm0 + wm * 16 + rq + q;
    const float mean = acc[0][q] + bm_;
    const float rs = acc[1][q] + bsd;
    const float sp = fmaxf(rs, 0.f) + log1pf(expf(-fabsf(rs)));
    const float sd = sp + 0.1f;
    const long long o = (long long)row * 256 + col;
    const float st = mean + sd * S.noise[o];
    S.omean[o] = mean; S.ostd[o] = sd; S.ostate[o] = st;
    S.stateb[o] = f2bf(st);
  }
}

extern "C" void kernel_launch(void* const* d_in, const int* in_sizes, int n_in,
                              void* d_out, int out_size, void* d_ws, size_t ws_size,
                              hipStream_t stream) {
  float* out = (float*)d_out;

  int gid = 0;
  if (n_in != 26) gid = 1;
  else if (out_size != 83886080) gid = 2;
  else if (in_sizes[0] != 262144 || in_sizes[1] != 1048576 || in_sizes[2] != 33554432 ||
           in_sizes[3] != 196608 || in_sizes[4] != 8388608 || in_sizes[5] != 8388608) gid = 3;
  else if (in_sizes[6] != 1572864 || in_sizes[8] != 548864) gid = 4;
  else if (in_sizes[10] != 3145728 || in_sizes[11] != 3145728 ||
           in_sizes[14] != 3145728 || in_sizes[15] != 3145728) gid = 5;
  else if (in_sizes[18] != 1048576 || in_sizes[20] != 524288 ||
           in_sizes[22] != 1048576 || in_sizes[24] != 524288) gid = 6;
  else if (ws_size < (184ull << 20)) gid = 7;
  if (gid != 0) {
    unsigned wsMB = (unsigned)(ws_size >> 20); if (wsMB > 4095u) wsMB = 4095u;
    const float K = (float)gid * 16777216.0f + (float)wsMB;
    hipLaunchKernelGGL(marker_k, dim3(1), dim3(64), 0, stream, out, K);
    return;
  }

  const float* prev_state  = (const float*)d_in[0];
  const float* prev_belief = (const float*)d_in[1];
  const float* observations= (const float*)d_in[2];
  const float* poses       = (const float*)d_in[3];
  const float* noise_post  = (const float*)d_in[4];
  const float* noise_prior = (const float*)d_in[5];
  const float* W_esq = (const float*)d_in[6];  const float* b_esq = (const float*)d_in[7];
  const float* W_esp = (const float*)d_in[8];  const float* b_esp = (const float*)d_in[9];
  const float* gq_wih = (const float*)d_in[10]; const float* gq_whh = (const float*)d_in[11];
  const float* gq_bih = (const float*)d_in[12]; const float* gq_bhh = (const float*)d_in[13];
  const float* gp_wih = (const float*)d_in[14]; const float* gp_whh = (const float*)d_in[15];
  const float* gp_bih = (const float*)d_in[16]; const float* gp_bhh = (const float*)d_in[17];
  const float* W_ebq = (const float*)d_in[18]; const float* b_ebq = (const float*)d_in[19];
  const float* W_sq  = (const float*)d_in[20]; const float* b_sq  = (const float*)d_in[21];
  const float* W_ebp = (const float*)d_in[22]; const float* b_ebp = (const float*)d_in[23];
  const float* W_sp  = (const float*)d_in[24]; const float* b_sp  = (const float*)d_in[25];

  float* out_belief = out;
  float* out_pstate = out + 33554432LL;
  float* out_pmean  = out + 41943040LL;
  float* out_pstd   = out + 50331648LL;
  float* out_qstate = out + 58720256LL;
  float* out_qmean  = out + 67108864LL;
  float* out_qstd   = out + 75497472LL;

  char* w = (char*)d_ws;
  ushort_t* obsb  = (ushort_t*)(w);                      // [0,64) MB
  ushort_t* OBSQ  = (ushort_t*)(w + (64ull << 20));      // [64,128) obs@Wesq' bf16
  ushort_t* wWesq = (ushort_t*)(w + (128ull << 20));
  ushort_t* wWesp = (ushort_t*)(w + (131ull << 20));
  ushort_t* wGqih = (ushort_t*)(w + (132ull << 20));
  ushort_t* wGqhh = (ushort_t*)(w + (138ull << 20));
  ushort_t* wGpih = (ushort_t*)(w + (144ull << 20));
  ushort_t* wGphh = (ushort_t*)(w + (150ull << 20));
  ushort_t* wEbq  = (ushort_t*)(w + (156ull << 20));
  ushort_t* wEbp  = (ushort_t*)(w + (158ull << 20));
  ushort_t* wSq   = (ushort_t*)(w + (160ull << 20));
  ushort_t* wSp   = (ushort_t*)(w + (161ull << 20));
  float*    wpe   = (float*)(w + (162ull << 20));
  ushort_t* h_q   = (ushort_t*)(w + (163ull << 20));
  ushort_t* h_p   = (ushort_t*)(w + (165ull << 20));
  ushort_t* bqb[2] = { (ushort_t*)(w + (167ull << 20)), (ushort_t*)(w + (169ull << 20)) };
  ushort_t* bpb[2] = { (ushort_t*)(w + (171ull << 20)), (ushort_t*)(w + (173ull << 20)) };
  ushort_t* sqb   = (ushort_t*)(w + (175ull << 20));
  ushort_t* spb   = (ushort_t*)(w + (175ull << 20) + 524288);
  float*    bpf[2] = { (float*)(w + (176ull << 20)), (float*)(w + (180ull << 20)) };

  const dim3 blk(256);
  auto cvt = [&](const float* s, ushort_t* d, long long n, int c, int ld, int off) {
    hipLaunchKernelGGL(cvt_k, dim3((unsigned)((n + 255) / 256)), blk, 0, stream, s, d, n, c, ld, off);
  };
  cvt(observations, obsb, 33554432LL, 1024, 1024, 0);
  cvt(W_esq, wWesq, 1572864LL, 1536, 1536, 0);
  cvt(W_esp, wWesp, 524288LL, 512, 536, 24);
  cvt(gq_wih, wGqih, 3145728LL, 1024, 1024, 0);
  cvt(gq_whh, wGqhh, 3145728LL, 1024, 1024, 0);
  cvt(gp_wih, wGpih, 3145728LL, 1024, 1024, 0);
  cvt(gp_whh, wGphh, 3145728LL, 1024, 1024, 0);
  cvt(W_ebq, wEbq, 1048576LL, 1024, 1024, 0);
  cvt(W_ebp, wEbp, 1048576LL, 1024, 1024, 0);
  cvt(W_sq, wSq, 524288LL, 1024, 1024, 0);
  cvt(W_sp, wSp, 524288LL, 1024, 1024, 0);
  cvt(prev_state, sqb, 262144LL, 256, 256, 0);
  cvt(prev_state, spb, 262144LL, 256, 256, 0);
  cvt(prev_belief, bqb[1], 1048576LL, 1024, 1024, 0);
  cvt(prev_belief, bpb[1], 1048576LL, 1024, 1024, 0);
  hipLaunchKernelGGL(wpe_k, dim3(24), blk, 0, stream, W_esp, wpe);

  // one-time batched obs GEMM (recurrence-independent)
  {
    ObsqArgs oa{ obsb, wWesq, OBSQ };
    hipLaunchKernelGGL(obsq_k, dim3(8, 512), blk, 0, stream, oa);
  }

  for (int t = 0; t < T1_; ++t) {
    const int cur = t & 1, prv = cur ^ 1;
    const float* bq_prev_f = (t == 0) ? prev_belief : out_belief + (long long)(t - 1) * 1048576;
    const float* bp_prev_f = (t == 0) ? prev_belief : bpf[prv];

    MM2Args a{};
    a.s[0] = MMSide{ sqb, spb, nullptr, 256, 256, 0, 1024, 1280, 0,
                     wWesq, 1536, b_esq, h_q, 0, OBSQ + (long long)t * 1048576 };
    a.s[1] = MMSide{ sqb, spb, nullptr, 256, 256, 0, 0, 256, 0,
                     wWesp, 512, b_esp, h_p, 1, nullptr };
    a.poses_t = poses + (long long)t * 6144; a.wpe = wpe;
    hipLaunchKernelGGL(mm2_k, dim3(8, 32, 2), blk, 0, stream, a);

    Gru2Args gr{};
    gr.s[0] = GruSide{ h_q, bqb[prv], bq_prev_f, wGqih, wGqhh, gq_bih, gq_bhh,
                       out_belief + (long long)t * 1048576, bqb[cur] };
    gr.s[1] = GruSide{ h_p, bpb[prv], bp_prev_f, wGpih, wGphh, gp_bih, gp_bhh,
                       bpf[cur], bpb[cur] };
    hipLaunchKernelGGL(gru2_k, dim3(16, 16, 2), blk, 0, stream, gr);

    a = MM2Args{};
    a.s[0] = MMSide{ bqb[cur], nullptr, nullptr, 1024, 0, 0, 0, 0, 0,
                     wEbq, 1024, b_ebq, h_q, 0, nullptr };
    a.s[1] = MMSide{ bpb[cur], nullptr, nullptr, 1024, 0, 0, 0, 0, 0,
                     wEbp, 1024, b_ebp, h_p, 0, nullptr };
    hipLaunchKernelGGL(mm2_k, dim3(8, 32, 2), blk, 0, stream, a);

    Head2Args hd{};
    hd.s[0] = HeadSide{ h_q, wSq, b_sq, noise_post + (long long)t * 262144,
                        out_qmean + (long long)t * 262144,
                        out_qstd + (long long)t * 262144,
                        out_qstate + (long long)t * 262144, sqb };
    hd.s[1] = HeadSide{ h_p, wSp, b_sp, noise_prior + (long long)t * 262144,
                        out_pmean + (long long)t * 262144,
                        out_pstd + (long long)t * 262144,
                        out_pstate + (long long)t * 262144, spb };
    hipLaunchKernelGGL(head2_k, dim3(8, 32, 2), blk, 0, stream, hd);
  }
}

// Round 15
// 3439.539 us; speedup vs baseline: 1.0076x; 1.0076x over previous
//
#include <hip/hip_runtime.h>
#include <stdint.h>
#include <math.h>

typedef unsigned short ushort_t;
typedef __attribute__((ext_vector_type(8))) short bf16x8;
typedef __attribute__((ext_vector_type(4))) float f32x4;

#define T1_ 32

// raw barrier + counted vmcnt (T4): prefetch stays in flight across the barrier.
#define SW_BAR() asm volatile("s_barrier" ::: "memory")
#define SW_VM(n) asm volatile("s_waitcnt vmcnt(" #n ")" ::: "memory")

__device__ __forceinline__ float bf2f(ushort_t u) {
  union { unsigned int i; float f; } v; v.i = ((unsigned int)u) << 16; return v.f;
}
__device__ __forceinline__ ushort_t f2bf(float f) {
  union { float f; unsigned int i; } v; v.f = f;
  unsigned int x = v.i;
  return (ushort_t)((x + 0x7FFFu + ((x >> 16) & 1u)) >> 16); // RNE
}
__device__ __forceinline__ float sigm(float x) { return 1.f / (1.f + expf(-x)); }

__device__ __forceinline__ void gld16(const ushort_t* g, ushort_t* l) {
  __builtin_amdgcn_global_load_lds(
      (const __attribute__((address_space(1))) unsigned int*)g,
      (__attribute__((address_space(3))) unsigned int*)l, 16, 0, 0);
}

// XOR-chunk swizzle (R11, verified): staging lane l -> (row=l>>2, chunk=(l^(l>>2)^(l>>4))&3);
// reader lane l wants (row r=l&15, chunk q=l>>4) -> slot (r<<2)|((q^r^(r>>2))&3).
// Coalesced 64B/row staging + conflict-free (2-way) ds_read_b128.

__global__ __launch_bounds__(256) void cvt_k(const float* src, ushort_t* dst,
                                             long long n, int cols, int src_ld, int src_off) {
  const long long idx = (long long)blockIdx.x * 256 + threadIdx.x;
  if (idx >= n) return;
  const long long row = idx / cols;
  const int col = (int)(idx - row * cols);
  dst[idx] = f2bf(src[row * src_ld + src_off + col]);
}

__global__ __launch_bounds__(256) void wpe_k(const float* Wesp, float* wpe) {
  const int i = blockIdx.x * 256 + threadIdx.x;
  if (i >= 1024 * 6) return;
  const int n = i / 6, j = i % 6;
  float s = 0.f;
#pragma unroll
  for (int r = 0; r < 4; ++r) s += Wesp[(long long)n * 536 + j + 6 * r];
  wpe[i] = s;
}

__global__ void marker_k(float* out, float K) {
  if (threadIdx.x == 0 && blockIdx.x == 0) out[0] = K;
}

// ---- one-time batched obs GEMM: OBSQ[32768 x 1024] = obsb @ Wesq[:, :1024]^T (bf16 out) ----
struct ObsqArgs { const ushort_t* A; const ushort_t* W; ushort_t* out; };
__global__ __launch_bounds__(256) void obsq_k(ObsqArgs g) {
  __shared__ __align__(16) ushort_t As[2][2048];
  __shared__ __align__(16) ushort_t Ws[2][4096];
  const int tid = threadIdx.x;
  const int lane = tid & 63, wv = tid >> 6;
  const int wm = wv >> 1, wn = wv & 1;
  const int bn0 = blockIdx.x * 128, bm0 = blockIdx.y * 64;
  const int srow = lane >> 2;
  const int sch8 = ((lane ^ (lane >> 2) ^ (lane >> 4)) & 3) * 8;
  const int rr = lane & 15, qq = lane >> 4;
  const int rslot8 = (((rr << 2) | ((qq ^ rr ^ (rr >> 2)) & 3)) * 8);

  f32x4 acc[2][4];
#pragma unroll
  for (int i = 0; i < 2; ++i)
#pragma unroll
    for (int j = 0; j < 4; ++j) acc[i][j] = (f32x4){0.f, 0.f, 0.f, 0.f};

  auto stage = [&](int buf, int kt) {
    const int k0 = kt * 32;
    gld16(g.A + (size_t)(bm0 + wv * 16 + srow) * 1024 + k0 + sch8, &As[buf][wv * 512]);
    gld16(g.W + (size_t)(bn0 + wv * 16 + srow) * 1536 + k0 + sch8, &Ws[buf][wv * 512]);
    gld16(g.W + (size_t)(bn0 + 64 + wv * 16 + srow) * 1536 + k0 + sch8,
          &Ws[buf][2048 + wv * 512]);
  };

  stage(0, 0);
  int cur = 0;
#pragma unroll 1
  for (int kt = 0; kt < 32; ++kt) {
    if (kt + 1 < 32) { stage(cur ^ 1, kt + 1); SW_VM(3); } else { SW_VM(0); }
    SW_BAR();
    bf16x8 a[2], b[4];
#pragma unroll
    for (int i = 0; i < 2; ++i)
      a[i] = *(const bf16x8*)&As[cur][(wm * 2 + i) * 512 + rslot8];
#pragma unroll
    for (int j = 0; j < 4; ++j)
      b[j] = *(const bf16x8*)&Ws[cur][(wn * 4 + j) * 512 + rslot8];
#pragma unroll
    for (int i = 0; i < 2; ++i)
#pragma unroll
      for (int j = 0; j < 4; ++j)
        acc[i][j] = __builtin_amdgcn_mfma_f32_16x16x32_bf16(a[i], b[j], acc[i][j], 0, 0, 0);
    if (kt + 1 < 32) SW_BAR();
    cur ^= 1;
  }

  const int r15 = lane & 15, rq = (lane >> 4) * 4;
#pragma unroll
  for (int i = 0; i < 2; ++i)
#pragma unroll
    for (int j = 0; j < 4; ++j) {
      const int col = bn0 + wn * 64 + j * 16 + r15;
#pragma unroll
      for (int q = 0; q < 4; ++q) {
        const int row = bm0 + wm * 32 + i * 16 + rq + q;
        g.out[(size_t)row * 1024 + col] = f2bf(acc[i][j][q]);
      }
    }
}

// ---- fused 2-sided GEMM: BM=32, BN=128, BK=32; 256 thr (4 waves, wn=wv); dbuf ----
struct MMSide {
  const ushort_t* a0; const ushort_t* a1; const ushort_t* a2;
  int kd0, kd1, kd2;
  int coff0, coff1, coff2;
  const ushort_t* W; int ldw;
  const float* bias;
  ushort_t* outb;
  int dopose;
  const ushort_t* extrab;   // optional full-width bf16 pre-activation add [1024x1024]
};
struct MM2Args { MMSide s[2]; const float* poses_t; const float* wpe; };

__global__ __launch_bounds__(256) void mm2_k(MM2Args g) {
  const MMSide S = g.s[blockIdx.z];
  __shared__ __align__(16) ushort_t As[2][1024];
  __shared__ __align__(16) ushort_t Ws[2][4096];
  const int tid = threadIdx.x;
  const int lane = tid & 63, wv = tid >> 6;
  const int wn = wv;
  const int bn0 = blockIdx.x * 128, bm0 = blockIdx.y * 32;
  const int srow = lane >> 2;
  const int sch8 = ((lane ^ (lane >> 2) ^ (lane >> 4)) & 3) * 8;
  const int rr = lane & 15, qq = lane >> 4;
  const int rslot8 = (((rr << 2) | ((qq ^ rr ^ (rr >> 2)) & 3)) * 8);

  f32x4 acc[2][2];
#pragma unroll
  for (int i = 0; i < 2; ++i)
#pragma unroll
    for (int j = 0; j < 2; ++j) acc[i][j] = (f32x4){0.f, 0.f, 0.f, 0.f};

  const int nk0 = S.kd0 >> 5, nk1 = S.kd1 >> 5, nk2 = S.kd2 >> 5;
  const int c1 = nk0, c2 = nk0 + nk1, nkt = c2 + nk2;

  auto stage = [&](int buf, int ktg) {
    const ushort_t* ab; int ktl, kdim, cf;
    if (ktg < c1)      { ab = S.a0; ktl = ktg;      kdim = S.kd0; cf = S.coff0; }
    else if (ktg < c2) { ab = S.a1; ktl = ktg - c1; kdim = S.kd1; cf = S.coff1; }
    else               { ab = S.a2; ktl = ktg - c2; kdim = S.kd2; cf = S.coff2; }
    const int k0 = ktl * 32;
    gld16(S.W + cf + (size_t)(bn0 + wv * 16 + srow) * S.ldw + k0 + sch8, &Ws[buf][wv * 512]);
    gld16(S.W + cf + (size_t)(bn0 + 64 + wv * 16 + srow) * S.ldw + k0 + sch8,
          &Ws[buf][(wv + 4) * 512]);
    if (wv < 2)
      gld16(ab + (size_t)(bm0 + wv * 16 + srow) * kdim + k0 + sch8, &As[buf][wv * 512]);
  };

  stage(0, 0);
  int cur = 0;
#pragma unroll 1
  for (int ktg = 0; ktg < nkt; ++ktg) {
    if (ktg + 1 < nkt) {
      stage(cur ^ 1, ktg + 1);
      if (wv < 2) { SW_VM(3); } else { SW_VM(2); }
    } else { SW_VM(0); }
    SW_BAR();
    bf16x8 a[2], b[2];
#pragma unroll
    for (int i = 0; i < 2; ++i)
      a[i] = *(const bf16x8*)&As[cur][i * 512 + rslot8];
#pragma unroll
    for (int j = 0; j < 2; ++j)
      b[j] = *(const bf16x8*)&Ws[cur][(wn * 2 + j) * 512 + rslot8];
#pragma unroll
    for (int i = 0; i < 2; ++i)
#pragma unroll
      for (int j = 0; j < 2; ++j)
        acc[i][j] = __builtin_amdgcn_mfma_f32_16x16x32_bf16(a[i], b[j], acc[i][j], 0, 0, 0);
    if (ktg + 1 < nkt) SW_BAR();
    cur ^= 1;
  }

  const int r15 = lane & 15, rq = (lane >> 4) * 4;
#pragma unroll
  for (int i = 0; i < 2; ++i) {
#pragma unroll
    for (int j = 0; j < 2; ++j) {
      const int col = bn0 + wn * 32 + j * 16 + r15;
      const float bs = S.bias[col];
#pragma unroll
      for (int q = 0; q < 4; ++q) {
        const int row = bm0 + i * 16 + rq + q;
        float v = acc[i][j][q] + bs;
        if (S.extrab) v += bf2f(S.extrab[(size_t)row * 1024 + col]);
        if (S.dopose) {
          float s = 0.f;
#pragma unroll
          for (int jj = 0; jj < 6; ++jj)
            s += g.poses_t[(long long)row * 6 + jj] * g.wpe[col * 6 + jj];
          v += s;
        }
        v = fmaxf(v, 0.f);
        S.outb[(size_t)row * 1024 + col] = f2bf(v);
      }
    }
  }
}

// ---- fused 2-sided GRU: BM=64, BN=64, 256 thr (4 waves 2x2), dbuf ----
struct GruSide {
  const ushort_t* x;
  const ushort_t* hb;
  const float* hf;
  const ushort_t* wih; const ushort_t* whh;
  const float* bih; const float* bhh;
  float* dst; ushort_t* dstb;    // ping-pong: dstb != hb
};
struct Gru2Args { GruSide s[2]; };

__global__ __launch_bounds__(256) void gru2_k(Gru2Args g) {
  const GruSide S = g.s[blockIdx.z];
  __shared__ __align__(16) ushort_t lds[2][16384];  // 64 KB
  const int tid = threadIdx.x;
  const int lane = tid & 63, wv = tid >> 6;
  const int wm = wv >> 1, wn = wv & 1;
  const int bn0 = blockIdx.x * 64, bm0 = blockIdx.y * 64;
  const int srow = lane >> 2;
  const int sch8 = ((lane ^ (lane >> 2) ^ (lane >> 4)) & 3) * 8;
  const int rr = lane & 15, qq = lane >> 4;
  const int rslot8 = (((rr << 2) | ((qq ^ rr ^ (rr >> 2)) & 3)) * 8);

  f32x4 aR[2][2], aZ[2][2], aNI[2][2], aNH[2][2];
#pragma unroll
  for (int i = 0; i < 2; ++i)
#pragma unroll
    for (int j = 0; j < 2; ++j) {
      aR[i][j] = (f32x4){0.f,0.f,0.f,0.f}; aZ[i][j] = (f32x4){0.f,0.f,0.f,0.f};
      aNI[i][j] = (f32x4){0.f,0.f,0.f,0.f}; aNH[i][j] = (f32x4){0.f,0.f,0.f,0.f};
    }

  auto stage = [&](int buf, int kt) {
    const int k0 = kt * 32;
#pragma unroll
    for (int u = 0; u < 8; ++u) {
      const int G = wv * 8 + u;
      if (G < 4)
        gld16(S.x + (size_t)(bm0 + G * 16 + srow) * 1024 + k0 + sch8, &lds[buf][G * 512]);
      else if (G < 8)
        gld16(S.hb + (size_t)(bm0 + (G - 4) * 16 + srow) * 1024 + k0 + sch8, &lds[buf][G * 512]);
      else {
        const int wch = G - 8, gg = wch >> 2, rc = wch & 3;
        const ushort_t* base = (gg < 3) ? S.wih : S.whh;
        const int gr = (gg < 3 ? gg : gg - 3) * 1024 + bn0 + rc * 16 + srow;
        gld16(base + (size_t)gr * 1024 + k0 + sch8, &lds[buf][G * 512]);
      }
    }
  };

  stage(0, 0);
  int cur = 0;
#pragma unroll 1
  for (int kt = 0; kt < 32; ++kt) {
    if (kt + 1 < 32) { stage(cur ^ 1, kt + 1); SW_VM(8); } else { SW_VM(0); }
    SW_BAR();
    bf16x8 ax[2], ah[2], w[6][2];
#pragma unroll
    for (int i = 0; i < 2; ++i) {
      ax[i] = *(const bf16x8*)&lds[cur][(wm * 2 + i) * 512 + rslot8];
      ah[i] = *(const bf16x8*)&lds[cur][(4 + wm * 2 + i) * 512 + rslot8];
    }
#pragma unroll
    for (int gg = 0; gg < 6; ++gg)
#pragma unroll
      for (int j = 0; j < 2; ++j)
        w[gg][j] = *(const bf16x8*)&lds[cur][(8 + gg * 4 + wn * 2 + j) * 512 + rslot8];
#pragma unroll
    for (int i = 0; i < 2; ++i)
#pragma unroll
      for (int j = 0; j < 2; ++j) {
        aR[i][j]  = __builtin_amdgcn_mfma_f32_16x16x32_bf16(ax[i], w[0][j], aR[i][j], 0, 0, 0);
        aR[i][j]  = __builtin_amdgcn_mfma_f32_16x16x32_bf16(ah[i], w[3][j], aR[i][j], 0, 0, 0);
        aZ[i][j]  = __builtin_amdgcn_mfma_f32_16x16x32_bf16(ax[i], w[1][j], aZ[i][j], 0, 0, 0);
        aZ[i][j]  = __builtin_amdgcn_mfma_f32_16x16x32_bf16(ah[i], w[4][j], aZ[i][j], 0, 0, 0);
        aNI[i][j] = __builtin_amdgcn_mfma_f32_16x16x32_bf16(ax[i], w[2][j], aNI[i][j], 0, 0, 0);
        aNH[i][j] = __builtin_amdgcn_mfma_f32_16x16x32_bf16(ah[i], w[5][j], aNH[i][j], 0, 0, 0);
      }
    if (kt + 1 < 32) SW_BAR();
    cur ^= 1;
  }

  const int r15 = lane & 15, rq = (lane >> 4) * 4;
#pragma unroll
  for (int j = 0; j < 2; ++j) {
    const int col = bn0 + wn * 32 + j * 16 + r15;
    const float brz = S.bih[col] + S.bhh[col];
    const float bzz = S.bih[col + 1024] + S.bhh[col + 1024];
    const float bni = S.bih[col + 2048], bnh = S.bhh[col + 2048];
#pragma unroll
    for (int i = 0; i < 2; ++i) {
#pragma unroll
      for (int q = 0; q < 4; ++q) {
        const int row = bm0 + wm * 32 + i * 16 + rq + q;
        const float r = sigm(aR[i][j][q] + brz);
        const float z = sigm(aZ[i][j][q] + bzz);
        const float ng = tanhf(aNI[i][j][q] + bni + r * (aNH[i][j][q] + bnh));
        const size_t o = (size_t)row * 1024 + col;
        const float bnew = (1.f - z) * ng + z * S.hf[o];
        S.dst[o] = bnew;
        S.dstb[o] = f2bf(bnew);
      }
    }
  }
}

// ---- fused 2-sided head: BM=32, BN=32, 256 thr (4 waves 2x2), dbuf ----
struct HeadSide {
  const ushort_t* hh;
  const ushort_t* Ws;    // [512x1024]: rows [0,256)=mean, [256,512)=raw
  const float* bs;
  const float* noise;
  float* omean; float* ostd; float* ostate;
  ushort_t* stateb;
};
struct Head2Args { HeadSide s[2]; };

__global__ __launch_bounds__(256) void head2_k(Head2Args g) {
  const HeadSide S = g.s[blockIdx.z];
  __shared__ __align__(16) ushort_t lds[2][3072];
  const int tid = threadIdx.x;
  const int lane = tid & 63, wv = tid >> 6;
  const int wm = wv >> 1, wn = wv & 1;
  const int bn0 = blockIdx.x * 32, bm0 = blockIdx.y * 32;
  const int srow = lane >> 2;
  const int sch8 = ((lane ^ (lane >> 2) ^ (lane >> 4)) & 3) * 8;
  const int rr = lane & 15, qq = lane >> 4;
  const int rslot8 = (((rr << 2) | ((qq ^ rr ^ (rr >> 2)) & 3)) * 8);

  f32x4 acc[2];
#pragma unroll
  for (int gg = 0; gg < 2; ++gg) acc[gg] = (f32x4){0.f, 0.f, 0.f, 0.f};

  auto stage = [&](int buf, int kt) {
    const int k0 = kt * 32;
    if (wv < 2) {
      gld16(S.hh + (size_t)(bm0 + wv * 16 + srow) * 1024 + k0 + sch8, &lds[buf][wv * 512]);
      gld16(S.Ws + (size_t)(bn0 + wv * 16 + srow) * 1024 + k0 + sch8, &lds[buf][(2 + wv) * 512]);
    } else {
      gld16(S.Ws + (size_t)(256 + bn0 + (wv - 2) * 16 + srow) * 1024 + k0 + sch8,
            &lds[buf][(2 + wv) * 512]);
    }
  };

  stage(0, 0);
  int cur = 0;
#pragma unroll 1
  for (int kt = 0; kt < 32; ++kt) {
    if (kt + 1 < 32) {
      stage(cur ^ 1, kt + 1);
      if (wv < 2) { SW_VM(2); } else { SW_VM(1); }
    } else { SW_VM(0); }
    SW_BAR();
    const bf16x8 a = *(const bf16x8*)&lds[cur][wm * 512 + rslot8];
    const bf16x8 w0 = *(const bf16x8*)&lds[cur][(2 + wn) * 512 + rslot8];
    const bf16x8 w1 = *(const bf16x8*)&lds[cur][(4 + wn) * 512 + rslot8];
    acc[0] = __builtin_amdgcn_mfma_f32_16x16x32_bf16(a, w0, acc[0], 0, 0, 0);
    acc[1] = __builtin_amdgcn_mfma_f32_16x16x32_bf16(a, w1, acc[1], 0, 0, 0);
    if (kt + 1 < 32) SW_BAR();
    cur ^= 1;
  }

  const int r15 = lane & 15, rq = (lane >> 4) * 4;
  const int col = bn0 + wn * 16 + r15;
  const float bm_ = S.bs[col];
  const float bsd = S.bs[col + 256];
#pragma unroll
  for (int q = 0; q < 4; ++q) {
    const int row = bm0 + wm * 16 + rq + q;
    const float mean = acc[0][q] + bm_;
    const float rs = acc[1][q] + bsd;
    const float sp = fmaxf(rs, 0.f) + log1pf(expf(-fabsf(rs)));
    const float sd = sp + 0.1f;
    const long long o = (long long)row * 256 + col;
    const float st = mean + sd * S.noise[o];
    S.omean[o] = mean; S.ostd[o] = sd; S.ostate[o] = st;
    S.stateb[o] = f2bf(st);
  }
}

extern "C" void kernel_launch(void* const* d_in, const int* in_sizes, int n_in,
                              void* d_out, int out_size, void* d_ws, size_t ws_size,
                              hipStream_t stream) {
  float* out = (float*)d_out;

  int gid = 0;
  if (n_in != 26) gid = 1;
  else if (out_size != 83886080) gid = 2;
  else if (in_sizes[0] != 262144 || in_sizes[1] != 1048576 || in_sizes[2] != 33554432 ||
           in_sizes[3] != 196608 || in_sizes[4] != 8388608 || in_sizes[5] != 8388608) gid = 3;
  else if (in_sizes[6] != 1572864 || in_sizes[8] != 548864) gid = 4;
  else if (in_sizes[10] != 3145728 || in_sizes[11] != 3145728 ||
           in_sizes[14] != 3145728 || in_sizes[15] != 3145728) gid = 5;
  else if (in_sizes[18] != 1048576 || in_sizes[20] != 524288 ||
           in_sizes[22] != 1048576 || in_sizes[24] != 524288) gid = 6;
  else if (ws_size < (184ull << 20)) gid = 7;
  if (gid != 0) {
    unsigned wsMB = (unsigned)(ws_size >> 20); if (wsMB > 4095u) wsMB = 4095u;
    const float K = (float)gid * 16777216.0f + (float)wsMB;
    hipLaunchKernelGGL(marker_k, dim3(1), dim3(64), 0, stream, out, K);
    return;
  }

  const float* prev_state  = (const float*)d_in[0];
  const float* prev_belief = (const float*)d_in[1];
  const float* observations= (const float*)d_in[2];
  const float* poses       = (const float*)d_in[3];
  const float* noise_post  = (const float*)d_in[4];
  const float* noise_prior = (const float*)d_in[5];
  const float* W_esq = (const float*)d_in[6];  const float* b_esq = (const float*)d_in[7];
  const float* W_esp = (const float*)d_in[8];  const float* b_esp = (const float*)d_in[9];
  const float* gq_wih = (const float*)d_in[10]; const float* gq_whh = (const float*)d_in[11];
  const float* gq_bih = (const float*)d_in[12]; const float* gq_bhh = (const float*)d_in[13];
  const float* gp_wih = (const float*)d_in[14]; const float* gp_whh = (const float*)d_in[15];
  const float* gp_bih = (const float*)d_in[16]; const float* gp_bhh = (const float*)d_in[17];
  const float* W_ebq = (const float*)d_in[18]; const float* b_ebq = (const float*)d_in[19];
  const float* W_sq  = (const float*)d_in[20]; const float* b_sq  = (const float*)d_in[21];
  const float* W_ebp = (const float*)d_in[22]; const float* b_ebp = (const float*)d_in[23];
  const float* W_sp  = (const float*)d_in[24]; const float* b_sp  = (const float*)d_in[25];

  float* out_belief = out;
  float* out_pstate = out + 33554432LL;
  float* out_pmean  = out + 41943040LL;
  float* out_pstd   = out + 50331648LL;
  float* out_qstate = out + 58720256LL;
  float* out_qmean  = out + 67108864LL;
  float* out_qstd   = out + 75497472LL;

  char* w = (char*)d_ws;
  ushort_t* obsb  = (ushort_t*)(w);                      // [0,64) MB
  ushort_t* OBSQ  = (ushort_t*)(w + (64ull << 20));      // [64,128) obs@Wesq' bf16
  ushort_t* wWesq = (ushort_t*)(w + (128ull << 20));
  ushort_t* wWesp = (ushort_t*)(w + (131ull << 20));
  ushort_t* wGqih = (ushort_t*)(w + (132ull << 20));
  ushort_t* wGqhh = (ushort_t*)(w + (138ull << 20));
  ushort_t* wGpih = (ushort_t*)(w + (144ull << 20));
  ushort_t* wGphh = (ushort_t*)(w + (150ull << 20));
  ushort_t* wEbq  = (ushort_t*)(w + (156ull << 20));
  ushort_t* wEbp  = (ushort_t*)(w + (158ull << 20));
  ushort_t* wSq   = (ushort_t*)(w + (160ull << 20));
  ushort_t* wSp   = (ushort_t*)(w + (161ull << 20));
  float*    wpe   = (float*)(w + (162ull << 20));
  ushort_t* h_q   = (ushort_t*)(w + (163ull << 20));
  ushort_t* h_p   = (ushort_t*)(w + (165ull << 20));
  ushort_t* bqb[2] = { (ushort_t*)(w + (167ull << 20)), (ushort_t*)(w + (169ull << 20)) };
  ushort_t* bpb[2] = { (ushort_t*)(w + (171ull << 20)), (ushort_t*)(w + (173ull << 20)) };
  ushort_t* sqb   = (ushort_t*)(w + (175ull << 20));
  ushort_t* spb   = (ushort_t*)(w + (175ull << 20) + 524288);
  float*    bpf[2] = { (float*)(w + (176ull << 20)), (float*)(w + (180ull << 20)) };

  const dim3 blk(256);
  auto cvt = [&](const float* s, ushort_t* d, long long n, int c, int ld, int off) {
    hipLaunchKernelGGL(cvt_k, dim3((unsigned)((n + 255) / 256)), blk, 0, stream, s, d, n, c, ld, off);
  };
  cvt(observations, obsb, 33554432LL, 1024, 1024, 0);
  cvt(W_esq, wWesq, 1572864LL, 1536, 1536, 0);
  cvt(W_esp, wWesp, 524288LL, 512, 536, 24);
  cvt(gq_wih, wGqih, 3145728LL, 1024, 1024, 0);
  cvt(gq_whh, wGqhh, 3145728LL, 1024, 1024, 0);
  cvt(gp_wih, wGpih, 3145728LL, 1024, 1024, 0);
  cvt(gp_whh, wGphh, 3145728LL, 1024, 1024, 0);
  cvt(W_ebq, wEbq, 1048576LL, 1024, 1024, 0);
  cvt(W_ebp, wEbp, 1048576LL, 1024, 1024, 0);
  cvt(W_sq, wSq, 524288LL, 1024, 1024, 0);
  cvt(W_sp, wSp, 524288LL, 1024, 1024, 0);
  cvt(prev_state, sqb, 262144LL, 256, 256, 0);
  cvt(prev_state, spb, 262144LL, 256, 256, 0);
  cvt(prev_belief, bqb[1], 1048576LL, 1024, 1024, 0);
  cvt(prev_belief, bpb[1], 1048576LL, 1024, 1024, 0);
  hipLaunchKernelGGL(wpe_k, dim3(24), blk, 0, stream, W_esp, wpe);

  // one-time batched obs GEMM (recurrence-independent)
  {
    ObsqArgs oa{ obsb, wWesq, OBSQ };
    hipLaunchKernelGGL(obsq_k, dim3(8, 512), blk, 0, stream, oa);
  }

  for (int t = 0; t < T1_; ++t) {
    const int cur = t & 1, prv = cur ^ 1;
    const float* bq_prev_f = (t == 0) ? prev_belief : out_belief + (long long)(t - 1) * 1048576;
    const float* bp_prev_f = (t == 0) ? prev_belief : bpf[prv];

    MM2Args a{};
    a.s[0] = MMSide{ sqb, spb, nullptr, 256, 256, 0, 1024, 1280, 0,
                     wWesq, 1536, b_esq, h_q, 0, OBSQ + (long long)t * 1048576 };
    a.s[1] = MMSide{ sqb, spb, nullptr, 256, 256, 0, 0, 256, 0,
                     wWesp, 512, b_esp, h_p, 1, nullptr };
    a.poses_t = poses + (long long)t * 6144; a.wpe = wpe;
    hipLaunchKernelGGL(mm2_k, dim3(8, 32, 2), blk, 0, stream, a);

    Gru2Args gr{};
    gr.s[0] = GruSide{ h_q, bqb[prv], bq_prev_f, wGqih, wGqhh, gq_bih, gq_bhh,
                       out_belief + (long long)t * 1048576, bqb[cur] };
    gr.s[1] = GruSide{ h_p, bpb[prv], bp_prev_f, wGpih, wGphh, gp_bih, gp_bhh,
                       bpf[cur], bpb[cur] };
    hipLaunchKernelGGL(gru2_k, dim3(16, 16, 2), blk, 0, stream, gr);

    a = MM2Args{};
    a.s[0] = MMSide{ bqb[cur], nullptr, nullptr, 1024, 0, 0, 0, 0, 0,
                     wEbq, 1024, b_ebq, h_q, 0, nullptr };
    a.s[1] = MMSide{ bpb[cur], nullptr, nullptr, 1024, 0, 0, 0, 0, 0,
                     wEbp, 1024, b_ebp, h_p, 0, nullptr };
    hipLaunchKernelGGL(mm2_k, dim3(8, 32, 2), blk, 0, stream, a);

    Head2Args hd{};
    hd.s[0] = HeadSide{ h_q, wSq, b_sq, noise_post + (long long)t * 262144,
                        out_qmean + (long long)t * 262144,
                        out_qstd + (long long)t * 262144,
                        out_qstate + (long long)t * 262144, sqb };
    hd.s[1] = HeadSide{ h_p, wSp, b_sp, noise_prior + (long long)t * 262144,
                        out_pmean + (long long)t * 262144,
                        out_pstd + (long long)t * 262144,
                        out_pstate + (long long)t * 262144, spb };
    hipLaunchKernelGGL(head2_k, dim3(8, 32, 2), blk, 0, stream, hd);
  }
}